// Round 11
// baseline (2256.518 us; speedup 1.0000x reference)
//
#include <hip/hip_runtime.h>
#include <math.h>

#define B_ 8192
#define H_ 1024
#define LDP0 136
#define LDT 148    // Td column stride (floats)

// k4 LDS layout (A only; B fragments come straight from L2-resident global):
//   A: 3 planes x 4 sections x 145 granules (16B), perm(r) = r ^ ((r&8)>>1)
#define A_SEC 145
#define A_GRN (12*A_SEC)            // 1740 granules = 27840 B

typedef short bfrag __attribute__((ext_vector_type(8)));
typedef float f4v  __attribute__((ext_vector_type(4)));

union U8 { unsigned short u[8]; uint4 v; };

__device__ __forceinline__ float sigf(float x){ return 1.0f/(1.0f+__expf(-x)); }

// pack high halves of two fp32 (bf16-valued) into one u32: [lo16=bf(f0), hi16=bf(f1)]
__device__ __forceinline__ unsigned int pkhi(unsigned int u1, unsigned int u0){
  return __builtin_amdgcn_perm(u1, u0, 0x07060302u);
}

// ---------------- K1: s1 = sigmoid(x @ W1 + b1) ----------------
__global__ void k1_s1(const float* __restrict__ x, const float* __restrict__ W1,
                      const float* __restrict__ b1, float* __restrict__ s1o){
  __shared__ float xs[16];
  int b = blockIdx.x, t = threadIdx.x;
  if(t < 16) xs[t] = x[b*16 + t];
  __syncthreads();
  for(int h = t; h < H_; h += 256){
    float acc = b1[h];
    #pragma unroll
    for(int j=0;j<16;j++) acc = __fmaf_rn(xs[j], W1[j*H_ + h], acc);
    s1o[(size_t)b*H_ + h] = sigf(acc);
  }
}

// ---------------- K2: s2 = sigmoid(softplus @ W2 + b2), softplus = -log(1-s1) ----
__global__ __launch_bounds__(256,3) void k2_s2(const float* __restrict__ s1,
                      const float* __restrict__ W2, const float* __restrict__ b2,
                      float* __restrict__ s2o){
  __shared__ __align__(16) float As[32*LDP0];
  __shared__ __align__(16) float Bs[32*LDP0];
  int t = threadIdx.x, tx = t & 15, ty = t >> 4;
  int m0 = blockIdx.x * 128, n0 = blockIdx.y * 128;
  int jj = t & 31, rb4 = (t >> 5) * 4;
  float acc[8][8];
  #pragma unroll
  for(int i=0;i<8;i++){
    #pragma unroll
    for(int k=0;k<8;k++) acc[i][k]=0.f; }

  for(int jt=0; jt<32; jt++){
    int j0 = jt*32;
    __syncthreads();
    #pragma unroll
    for(int g=0; g<4; g++){
      #pragma unroll
      for(int i=0;i<4;i++){
        int r = rb4 + i + 32*g;
        As[jj*LDP0 + r] = -__logf(1.0f - s1[(size_t)(m0+r)*H_ + j0 + jj]);
      }
    }
    { int jB = t >> 3, kb = (t & 7) * 16;
      const float* src = &W2[(size_t)(j0 + jB)*H_ + n0 + kb];
      #pragma unroll
      for(int c=0;c<4;c++) *(float4*)&Bs[jB*LDP0 + kb + 4*c] = *(const float4*)(src + 4*c);
    }
    __syncthreads();
    #pragma unroll 8
    for(int j=0;j<32;j++){
      float4 a0 = *(const float4*)&As[j*LDP0 + 8*ty];
      float4 a1f= *(const float4*)&As[j*LDP0 + 8*ty+4];
      float4 b0 = *(const float4*)&Bs[j*LDP0 + 4*tx];
      float4 b1f= *(const float4*)&Bs[j*LDP0 + 64 + 4*tx];
      float aa[8] = {a0.x,a0.y,a0.z,a0.w,a1f.x,a1f.y,a1f.z,a1f.w};
      float bb[8] = {b0.x,b0.y,b0.z,b0.w,b1f.x,b1f.y,b1f.z,b1f.w};
      #pragma unroll
      for(int i=0;i<8;i++){
        #pragma unroll
        for(int k=0;k<8;k++) acc[i][k] = __fmaf_rn(aa[i], bb[k], acc[i][k]); }
    }
  }
  float4 bb0 = *(const float4*)&b2[n0 + 4*tx];
  float4 bb1 = *(const float4*)&b2[n0 + 64 + 4*tx];
  #pragma unroll
  for(int i=0;i<8;i++){
    size_t r = (size_t)(m0 + 8*ty + i)*H_;
    float4 o0 = make_float4(sigf(acc[i][0]+bb0.x), sigf(acc[i][1]+bb0.y),
                            sigf(acc[i][2]+bb0.z), sigf(acc[i][3]+bb0.w));
    float4 o1 = make_float4(sigf(acc[i][4]+bb1.x), sigf(acc[i][5]+bb1.y),
                            sigf(acc[i][6]+bb1.z), sigf(acc[i][7]+bb1.w));
    *(float4*)&s2o[r + n0 + 4*tx] = o0;
    *(float4*)&s2o[r + n0 + 64 + 4*tx] = o1;
  }
}

// ---------------- K3: u = (w3*s2) @ W2^T ----------------
__global__ __launch_bounds__(256,3) void k3_u(const float* __restrict__ s2,
                      const float* __restrict__ W2, const float* __restrict__ W3,
                      float* __restrict__ u){
  __shared__ __align__(16) float As[32*LDP0];
  __shared__ __align__(16) float Bs[32*LDP0];
  int t = threadIdx.x, tx = t & 15, ty = t >> 4;
  int m0 = blockIdx.x * 128, n0 = blockIdx.y * 128;
  int jj = t & 31, rb4 = (t >> 5) * 4;
  float acc[8][8];
  #pragma unroll
  for(int i=0;i<8;i++){
    #pragma unroll
    for(int k=0;k<8;k++) acc[i][k]=0.f; }

  for(int kt=0; kt<32; kt++){
    int k0 = kt*32;
    __syncthreads();
    float w3v = W3[k0 + jj];
    #pragma unroll
    for(int g=0; g<4; g++){
      #pragma unroll
      for(int i=0;i<4;i++){
        int r = rb4 + i + 32*g;
        As[jj*LDP0 + r] = w3v * s2[(size_t)(m0+r)*H_ + k0 + jj];
      }
    }
    { int jcol = t >> 1, kb = (t & 1) * 16;
      const float* src = &W2[(size_t)(n0 + jcol)*H_ + k0 + kb];
      #pragma unroll
      for(int c=0;c<16;c++) Bs[(kb+c)*LDP0 + jcol] = src[c];
    }
    __syncthreads();
    #pragma unroll 8
    for(int j=0;j<32;j++){
      float4 a0 = *(const float4*)&As[j*LDP0 + 8*ty];
      float4 a1f= *(const float4*)&As[j*LDP0 + 8*ty+4];
      float4 b0 = *(const float4*)&Bs[j*LDP0 + 4*tx];
      float4 b1f= *(const float4*)&Bs[j*LDP0 + 64 + 4*tx];
      float aa[8] = {a0.x,a0.y,a0.z,a0.w,a1f.x,a1f.y,a1f.z,a1f.w};
      float bb[8] = {b0.x,b0.y,b0.z,b0.w,b1f.x,b1f.y,b1f.z,b1f.w};
      #pragma unroll
      for(int i=0;i<8;i++){
        #pragma unroll
        for(int k=0;k<8;k++) acc[i][k] = __fmaf_rn(aa[i], bb[k], acc[i][k]); }
    }
  }
  #pragma unroll
  for(int i=0;i<8;i++){
    size_t r = (size_t)(m0 + 8*ty + i)*H_;
    *(float4*)&u[r + n0 + 4*tx]      = make_float4(acc[i][0],acc[i][1],acc[i][2],acc[i][3]);
    *(float4*)&u[r + n0 + 64 + 4*tx] = make_float4(acc[i][4],acc[i][5],acc[i][6],acc[i][7]);
  }
}

// ---------------- KF: F64[j][p] = W1[8+(p>>3)][j]*W1[8+(p&7)][j] ----------------
__global__ void kF(const float* __restrict__ W1, float* __restrict__ F64){
  int e = blockIdx.x*256 + threadIdx.x;
  int j = e >> 6, p = e & 63;
  F64[e] = W1[(8+(p>>3))*H_ + j] * W1[(8+(p&7))*H_ + j];
}

// ---------------- K5a: Hz1M = D1 @ F64 ----------------
__global__ __launch_bounds__(256) void k5a(const float* __restrict__ s1,
                      const float* __restrict__ u, const float* __restrict__ F64,
                      float* __restrict__ Hz1M){
  __shared__ __align__(16) float As[32*72];
  __shared__ __align__(16) float Bs[32*72];
  int t = threadIdx.x, tx = t & 15, ty = t >> 4;
  int m0 = blockIdx.x * 64;
  int jj = t & 31, rb8 = (t >> 5) * 8;
  float acc[4][4];
  #pragma unroll
  for(int i=0;i<4;i++){
    #pragma unroll
    for(int k=0;k<4;k++) acc[i][k]=0.f; }

  for(int jt=0; jt<32; jt++){
    int j0 = jt*32;
    __syncthreads();
    #pragma unroll
    for(int g=0; g<8; g++){
      int r = rb8 + g;
      float s = s1[(size_t)(m0+r)*H_ + j0 + jj];
      As[jj*72 + r] = s*(1.0f-s)*u[(size_t)(m0+r)*H_ + j0 + jj];
    }
    { int jB = t >> 3, cb = (t & 7) * 8;
      const float* src = &F64[(j0 + jB)*64 + cb];
      *(float4*)&Bs[jB*72 + cb]   = *(const float4*)(src);
      *(float4*)&Bs[jB*72 + cb+4] = *(const float4*)(src+4);
    }
    __syncthreads();
    #pragma unroll 8
    for(int j=0;j<32;j++){
      float4 a4 = *(const float4*)&As[j*72 + 4*ty];
      float4 b4 = *(const float4*)&Bs[j*72 + 4*tx];
      float aa[4] = {a4.x,a4.y,a4.z,a4.w};
      float bb[4] = {b4.x,b4.y,b4.z,b4.w};
      #pragma unroll
      for(int i=0;i<4;i++){
        #pragma unroll
        for(int k=0;k<4;k++) acc[i][k] = __fmaf_rn(aa[i], bb[k], acc[i][k]); }
    }
  }
  #pragma unroll
  for(int i=0;i<4;i++)
    *(float4*)&Hz1M[(size_t)(m0+4*ty+i)*64 + 4*tx] =
      make_float4(acc[i][0],acc[i][1],acc[i][2],acc[i][3]);
}

// ---------------- K5b: dq16[b][0:8]=dLdq, [8:16]=c1 ----------------
__global__ void k5b(const float* __restrict__ s1, const float* __restrict__ u,
                    const float* __restrict__ W1, const float* __restrict__ x,
                    float* __restrict__ dq16){
  int wid = threadIdx.x >> 6, lane = threadIdx.x & 63;
  int b = blockIdx.x*4 + wid;
  float qd[8];
  #pragma unroll
  for(int i=0;i<8;i++) qd[i] = x[b*16 + 8 + i];
  float accd[8] = {0,0,0,0,0,0,0,0};
  float accc[8] = {0,0,0,0,0,0,0,0};
  for(int jb=0;jb<16;jb++){
    int j = jb*64 + lane;
    float s1v = s1[(size_t)b*H_+j], uv = u[(size_t)b*H_+j];
    float g1 = s1v*uv;
    float d1 = (1.0f - s1v)*g1;
    float w1q = 0.f;
    #pragma unroll
    for(int i=0;i<8;i++){ float w = W1[i*H_+j];
      accd[i] = __fmaf_rn(g1, w, accd[i]);
      w1q = __fmaf_rn(qd[i], w, w1q); }
    float dw = d1*w1q;
    #pragma unroll
    for(int m=0;m<8;m++) accc[m] = __fmaf_rn(dw, W1[(8+m)*H_+j], accc[m]);
  }
  #pragma unroll
  for(int i=0;i<8;i++){
    #pragma unroll
    for(int off=1; off<64; off<<=1){
      accd[i] += __shfl_xor(accd[i], off, 64);
      accc[i] += __shfl_xor(accc[i], off, 64);
    }
  }
  if(lane==0){
    #pragma unroll
    for(int i=0;i<8;i++){ dq16[b*16+i] = accd[i]; dq16[b*16+8+i] = accc[i]; }
  }
}

// ---------------- KW2T: W2 -> 3 transposed bf16 EXACT-truncation planes [k][j] ----
__global__ void kW2T(const float* __restrict__ W2, unsigned short* __restrict__ Wh,
                     unsigned short* __restrict__ Wm, unsigned short* __restrict__ Wl){
  __shared__ float tile[32][132];
  int j0 = blockIdx.x * 32, k0 = blockIdx.y * 128;
  int t = threadIdx.x;
  int lr = t >> 3, lc0 = (t & 7) * 16;
  const float* src = &W2[(size_t)(j0+lr)*H_ + k0 + lc0];
  #pragma unroll
  for(int c=0;c<16;c+=4) *(float4*)&tile[lr][lc0+c] = *(const float4*)(src + c);
  __syncthreads();
  int k = t >> 1;
  #pragma unroll
  for(int o2=0;o2<2;o2++){
    int oc = (t&1)*2 + o2;
    U8 uh, um2, ul2;
    #pragma unroll
    for(int e=0;e<8;e++){
      float a = tile[oc*8+e][k];
      unsigned int ua = __float_as_uint(a);
      unsigned int h = ua & 0xFFFF0000u;
      float r1 = __fsub_rn(a, __uint_as_float(h));        // exact, contraction-proof
      unsigned int m = __float_as_uint(r1) & 0xFFFF0000u;
      float l = __fsub_rn(r1, __uint_as_float(m));        // exactly bf16-representable
      uh.u[e]  = (unsigned short)(h >> 16);
      um2.u[e] = (unsigned short)(m >> 16);
      ul2.u[e] = (unsigned short)(__float_as_uint(l) >> 16);
    }
    size_t o = (size_t)(k0+k)*H_ + j0 + oc*8;
    *(uint4*)&Wh[o] = uh.v; *(uint4*)&Wm[o] = um2.v; *(uint4*)&Wl[o] = ul2.v;
  }
}

// ---------------- K4: bf16x8 exact-split MFMA T-GEMM + d2 contraction ----------------
// Block: 16 samples x 256 k-cols. Grid 2048 = 512 sgp x 4 kb2.
// B operand: wave wv consumes ONLY rows wv*64..wv*64+63, each granule exactly
// once -> the LDS round-trip for B was pure overhead (24 of ~58 wave LDS-ops).
// Load the three pre-split planes (6 MB, L2-resident) straight into the MFMA
// fragments; byte-identical to the staged path (perm is an involution:
// perm(wv*64+n2*16+pfm) = wv*64+n2*16+fr_m). Loads issue after barrier 1 and
// hide under the ~2500-cyc A-split stage (compiler-scheduled; round-9 lesson).
// Stays (256,2): 256-VGPR budget fits acc(AGPR)+48 bf VGPRs without the
// round-6 spill cliff (tripwire: GB-scale WRITE_SIZE = spill = revert).
__global__ __launch_bounds__(256,2) void k4_mfma(
    const float* __restrict__ s1, const float* __restrict__ s2,
    const float* __restrict__ x,  const float* __restrict__ W1,
    const unsigned short* __restrict__ W2Th, const unsigned short* __restrict__ W2Tm,
    const unsigned short* __restrict__ W2Tl,
    const float* __restrict__ W3, float* __restrict__ Mpart){
  __shared__ union {
    unsigned short A[A_GRN*8];
    float Td[64*LDT];
  } sm;
  __shared__ float qds[16][8];

  int t = threadIdx.x;
  int wv = t >> 6, lane = t & 63;
  int kb2 = blockIdx.x & 3, sgp = blockIdx.x >> 2;
  int b0 = sgp*16, k0 = kb2*256;

  if(t < 128){ int s = t>>3, i = t&7; qds[s][i] = x[(b0+s)*16 + 8+i]; }

  f4v acc[9][4];
  #pragma unroll
  for(int mt=0;mt<9;mt++){
    #pragma unroll
    for(int n2=0;n2<4;n2++){ acc[mt][n2][0]=0.f; acc[mt][n2][1]=0.f; acc[mt][n2][2]=0.f; acc[mt][n2][3]=0.f; }
  }

  int aoct = t & 3, arow = t >> 2;
  int fr_m = lane & 15, fr_q = lane >> 4;
  // swizzled A fragment-read granule base (jt-invariant)
  int pfm   = fr_m ^ ((fr_m & 8) >> 1);
  int aRd   = fr_q*A_SEC + pfm;                        // + p*4*A_SEC + mt*16

  for(int jt=0; jt<32; jt++){
    int j0 = jt*32;
    __syncthreads();
    // ---- B fragments: direct from global pre-split planes (no LDS) ----
    bfrag bf[4][3];
    #pragma unroll
    for(int n2=0;n2<4;n2++){
      int n = wv*64 + n2*16 + fr_m;
      size_t gb = (size_t)(k0+n)*H_ + j0 + fr_q*8;
      bf[n2][0] = *(const bfrag*)&W2Th[gb];
      bf[n2][1] = *(const bfrag*)&W2Tm[gb];
      bf[n2][2] = *(const bfrag*)&W2Tl[gb];
    }
    // ---- A stage: 144 rows x 32 j, exact 3-way truncation split ----
    #pragma unroll
    for(int pass=0; pass<3; pass++){
      int r = pass*64 + arow;
      if(r < 144){
        float4 w0, w1v, sa, sb;
        if(r < 128){
          int s = r>>3, m = r&7;
          const float* wp = &W1[(size_t)(8+m)*H_ + j0 + aoct*8];
          w0 = *(const float4*)wp; w1v = *(const float4*)(wp+4);
          const float* sp = &s1[(size_t)(b0+s)*H_ + j0 + aoct*8];
          sa = *(const float4*)sp; sb = *(const float4*)(sp+4);
        } else {
          int s = r - 128;
          float g0=0,g1=0,g2=0,g3=0,g4=0,g5=0,g6=0,g7=0;
          #pragma unroll
          for(int i=0;i<8;i++){
            float q = qds[s][i];
            const float* wp = &W1[(size_t)i*H_ + j0 + aoct*8];
            float4 a0 = *(const float4*)wp, a1 = *(const float4*)(wp+4);
            g0 = __fmaf_rn(q, a0.x, g0); g1 = __fmaf_rn(q, a0.y, g1);
            g2 = __fmaf_rn(q, a0.z, g2); g3 = __fmaf_rn(q, a0.w, g3);
            g4 = __fmaf_rn(q, a1.x, g4); g5 = __fmaf_rn(q, a1.y, g5);
            g6 = __fmaf_rn(q, a1.z, g6); g7 = __fmaf_rn(q, a1.w, g7);
          }
          w0 = make_float4(g0,g1,g2,g3); w1v = make_float4(g4,g5,g6,g7);
          const float* sp = &s1[(size_t)(b0+s)*H_ + j0 + aoct*8];
          sa = *(const float4*)sp; sb = *(const float4*)(sp+4);
        }
        float av[8];
        av[0]=__fmul_rn(w0.x,sa.x); av[1]=__fmul_rn(w0.y,sa.y);
        av[2]=__fmul_rn(w0.z,sa.z); av[3]=__fmul_rn(w0.w,sa.w);
        av[4]=__fmul_rn(w1v.x,sb.x); av[5]=__fmul_rn(w1v.y,sb.y);
        av[6]=__fmul_rn(w1v.z,sb.z); av[7]=__fmul_rn(w1v.w,sb.w);
        unsigned int uh[8], um[8], ul[8];
        #pragma unroll
        for(int e=0;e<8;e++){
          unsigned int ua = __float_as_uint(av[e]);
          unsigned int h = ua & 0xFFFF0000u;
          float r1 = __fsub_rn(av[e], __uint_as_float(h));   // exact
          unsigned int m = __float_as_uint(r1) & 0xFFFF0000u;
          float l = __fsub_rn(r1, __uint_as_float(m));       // exact
          uh[e]=h; um[e]=m; ul[e]=__float_as_uint(l);
        }
        int g0i = aoct*A_SEC + (r ^ ((r & 8) >> 1));   // plane 0 granule
        uint4 vh = make_uint4(pkhi(uh[1],uh[0]), pkhi(uh[3],uh[2]), pkhi(uh[5],uh[4]), pkhi(uh[7],uh[6]));
        uint4 vm = make_uint4(pkhi(um[1],um[0]), pkhi(um[3],um[2]), pkhi(um[5],um[4]), pkhi(um[7],um[6]));
        uint4 vl = make_uint4(pkhi(ul[1],ul[0]), pkhi(ul[3],ul[2]), pkhi(ul[5],ul[4]), pkhi(ul[7],ul[6]));
        *(uint4*)&sm.A[(g0i            )*8] = vh;
        *(uint4*)&sm.A[(g0i + 4*A_SEC  )*8] = vm;
        *(uint4*)&sm.A[(g0i + 8*A_SEC  )*8] = vl;
      }
    }
    __syncthreads();
    // ---- MFMA: one K=32 step, 8 split-terms, smallest-first ----
    #pragma unroll
    for(int mt=0; mt<9; mt++){
      bfrag a0 = *(bfrag*)&sm.A[(aRd             + mt*16)*8];
      bfrag a1v= *(bfrag*)&sm.A[(aRd + 4*A_SEC   + mt*16)*8];
      bfrag a2v= *(bfrag*)&sm.A[(aRd + 8*A_SEC   + mt*16)*8];
      #pragma unroll
      for(int n2=0;n2<4;n2++){
        f4v c = acc[mt][n2];
        c = __builtin_amdgcn_mfma_f32_16x16x32_bf16(a2v, bf[n2][1], c, 0,0,0); // 2^-24
        c = __builtin_amdgcn_mfma_f32_16x16x32_bf16(a1v, bf[n2][2], c, 0,0,0); // 2^-24
        c = __builtin_amdgcn_mfma_f32_16x16x32_bf16(a2v, bf[n2][0], c, 0,0,0); // 2^-16
        c = __builtin_amdgcn_mfma_f32_16x16x32_bf16(a0,  bf[n2][2], c, 0,0,0); // 2^-16
        c = __builtin_amdgcn_mfma_f32_16x16x32_bf16(a1v, bf[n2][1], c, 0,0,0); // 2^-16
        c = __builtin_amdgcn_mfma_f32_16x16x32_bf16(a1v, bf[n2][0], c, 0,0,0); // 2^-8
        c = __builtin_amdgcn_mfma_f32_16x16x32_bf16(a0,  bf[n2][1], c, 0,0,0); // 2^-8
        c = __builtin_amdgcn_mfma_f32_16x16x32_bf16(a0,  bf[n2][0], c, 0,0,0); // 1
        acc[mt][n2] = c;
      }
    }
  }

  // ---- epilogue: 4 phases of (dump one wave's 64 cols) + d2 contraction ----
  // Phases 0,1 -> kb = 2*kb2; phases 2,3 -> kb = 2*kb2+1 (each 128-col group
  // accumulated in the same order as the 128-col kernel -> bit-identical).
  float Mp[44];
  #pragma unroll
  for(int i=0;i<44;i++) Mp[i]=0.f;
  int es = t>>4, ec = t&15;
  const float* s2p = &s2[(size_t)(b0+es)*H_ + k0];

  #pragma unroll
  for(int ph=0; ph<4; ph++){
    __syncthreads();
    if(wv == ph){
      #pragma unroll
      for(int mt=0; mt<9; mt++){
        #pragma unroll
        for(int n2=0;n2<4;n2++){
          int col = n2*16 + fr_m;
          int rowb = mt*16 + fr_q*4;
          #pragma unroll
          for(int rg=0;rg<4;rg++)
            sm.Td[col*LDT + rowb + rg] = acc[mt][n2][rg];
        }
      }
    }
    __syncthreads();
    float4 s2v = *(const float4*)&s2p[ph*64 + ec*4];
    float4 w3v = *(const float4*)&W3[k0 + ph*64 + ec*4];
    float dv[4] = { w3v.x*s2v.x*(1.f-s2v.x), w3v.y*s2v.y*(1.f-s2v.y),
                    w3v.z*s2v.z*(1.f-s2v.z), w3v.w*s2v.w*(1.f-s2v.w) };
    #pragma unroll
    for(int e=0;e<4;e++){
      int col = ec*4+e;
      const float* tp = &sm.Td[col*LDT + es*8];
      float4 t0 = *(const float4*)tp, t1 = *(const float4*)(tp+4);
      float T8[8] = {t0.x,t0.y,t0.z,t0.w,t1.x,t1.y,t1.z,t1.w};
      float vv = sm.Td[col*LDT + 128 + es];
      float d = dv[e];
      int ix=0;
      #pragma unroll
      for(int m=0;m<8;m++){
        float w = __fmul_rn(T8[m], d);
        Mp[36+m] = __fmaf_rn(w, vv, Mp[36+m]);
        #pragma unroll
        for(int n=m;n<8;n++){ Mp[ix] = __fmaf_rn(w, T8[n], Mp[ix]); ix++; }
      }
    }
    if(ph & 1){
      // reduce over the 16 column-group lanes and write this kb group
      #pragma unroll
      for(int i=0;i<44;i++){
        #pragma unroll
        for(int off=1; off<16; off<<=1) Mp[i] += __shfl_xor(Mp[i], off, 64);
      }
      if(ec==0){
        int kb = kb2*2 + (ph>>1);
        float* o = &Mpart[((size_t)(b0+es)*8 + kb)*44];
        #pragma unroll
        for(int i=0;i<44;i++) o[i] = Mp[i];
      }
      #pragma unroll
      for(int i=0;i<44;i++) Mp[i]=0.f;
    }
  }
}

// ---------------- K6: assemble + f64 solve ----------------
__global__ __launch_bounds__(64) void k6(const float* __restrict__ x,
                    const float* __restrict__ Hz1M, const float* __restrict__ Mpart,
                    const float* __restrict__ dq16, float* __restrict__ out){
  __shared__ double A[64][73];
  int t = threadIdx.x;
  int b = blockIdx.x*64 + t;
  double* Ar = A[t];
  float qd[8];
  #pragma unroll
  for(int j=0;j<8;j++) qd[j] = x[b*16 + 8 + j];
  double Ms[44];
  #pragma unroll
  for(int i=0;i<44;i++) Ms[i]=0.0;
  for(int kb=0;kb<8;kb++){
    const float* mp = &Mpart[((size_t)b*8+kb)*44];
    #pragma unroll
    for(int i=0;i<44;i++) Ms[i] += (double)mp[i];
  }
  #pragma unroll
  for(int i=0;i<8;i++){
    #pragma unroll
    for(int j=0;j<8;j++) Ar[i*9+j] = (double)Hz1M[(size_t)b*64 + i*8 + j];
    Ar[i*9+8] = (double)dq16[b*16+i] - (double)dq16[b*16+8+i] - Ms[36+i];
  }
  { int ix=0;
    for(int m=0;m<8;m++)
      for(int n=m;n<8;n++){
        Ar[m*9+n] += Ms[ix];
        if(n>m) Ar[n*9+m] += Ms[ix];
        ix++;
      }
  }
  for(int c=0;c<8;c++){
    int piv = c; double best = fabs(Ar[c*9+c]);
    for(int rr=c+1; rr<8; rr++){ double v = fabs(Ar[rr*9+c]); if(v>best){best=v;piv=rr;} }
    if(piv!=c){
      for(int cc=c; cc<9; cc++){ double tmp=Ar[c*9+cc]; Ar[c*9+cc]=Ar[piv*9+cc]; Ar[piv*9+cc]=tmp; }
    }
    double inv = 1.0/Ar[c*9+c];
    for(int rr=c+1; rr<8; rr++){
      double f = Ar[rr*9+c]*inv;
      for(int cc=c+1; cc<9; cc++) Ar[rr*9+cc] -= f*Ar[c*9+cc];
    }
  }
  double sol[8];
  #pragma unroll
  for(int i=7;i>=0;i--){
    double s = Ar[i*9+8];
    #pragma unroll
    for(int j=i+1;j<8;j++) s -= Ar[i*9+j]*sol[j];
    sol[i] = s/Ar[i*9+i];
  }
  #pragma unroll
  for(int j=0;j<8;j++) out[b*16+j] = qd[j];
  #pragma unroll
  for(int i=0;i<8;i++) out[b*16+8+i] = (float)sol[i];
}

extern "C" void kernel_launch(void* const* d_in, const int* in_sizes, int n_in,
                              void* d_out, int out_size, void* d_ws, size_t ws_size,
                              hipStream_t stream){
  const float* x  = (const float*)d_in[0];
  const float* W1 = (const float*)d_in[1];
  const float* b1 = (const float*)d_in[2];
  const float* W2 = (const float*)d_in[3];
  const float* b2 = (const float*)d_in[4];
  const float* W3 = (const float*)d_in[5];
  float* out = (float*)d_out;

  float* ws   = (float*)d_ws;
  size_t BH   = (size_t)B_*H_;
  float* s1   = ws;                           // B*H
  float* s2   = s1  + BH;                     // B*H
  float* u    = s2  + BH;                     // B*H  (later: Mpart + W2T planes)
  float* F64  = u   + BH;                     // H*64
  float* Hz1M = F64 + (size_t)H_*64;          // B*64
  float* dq16 = Hz1M+ (size_t)B_*64;          // B*16

  // aliases inside u's 32 MB (u is dead after k5a/k5b):
  float* Mpart = u;                                        // B*8*44 fp32 = 11.5 MB
  unsigned short* W2Th = (unsigned short*)(u + 3145728);   // 12 MB offset, 2 MB
  unsigned short* W2Tm = W2Th + (size_t)H_*H_;             // 2 MB
  unsigned short* W2Tl = W2Tm + (size_t)H_*H_;             // 2 MB

  k1_s1 <<<dim3(B_),      dim3(256), 0, stream>>>(x, W1, b1, s1);
  k2_s2 <<<dim3(64,8),    dim3(256), 0, stream>>>(s1, W2, b2, s2);
  k3_u  <<<dim3(64,8),    dim3(256), 0, stream>>>(s2, W2, W3, u);
  kF    <<<dim3(256),     dim3(256), 0, stream>>>(W1, F64);
  k5a   <<<dim3(128),     dim3(256), 0, stream>>>(s1, u, F64, Hz1M);
  k5b   <<<dim3(2048),    dim3(256), 0, stream>>>(s1, u, W1, x, dq16);
  kW2T  <<<dim3(32,8),    dim3(256), 0, stream>>>(W2, W2Th, W2Tm, W2Tl);
  k4_mfma<<<dim3(2048),   dim3(256), 0, stream>>>(s1, s2, x, W1, W2Th, W2Tm, W2Tl, W3, Mpart);
  k6    <<<dim3(128),     dim3(64),  0, stream>>>(x, Hz1M, Mpart, dq16, out);
}

// Round 12
// 1932.128 us; speedup vs baseline: 1.1679x; 1.1679x over previous
//
#include <hip/hip_runtime.h>
#include <math.h>

#define B_ 8192
#define H_ 1024
#define LDP0 136
#define LDT 148    // Td column stride (floats)

// k4 LDS operand layout: 16B granules, [plane][q-section][perm(row)]
//   A: 3 planes x 4 sections x 145 granules (rows 0..143)
//   B: 3 planes x 4 sections x 257 granules (rows 0..255, 256-col tile)
//   perm(r) = r ^ ((r&8)>>1)  (involution)
#define A_SEC 145
#define B2_SEC 257
#define A_GRN (12*A_SEC)             // 1740 granules
#define B2_GRN (12*B2_SEC)           // 3084 granules
#define AB2_SH ((A_GRN + B2_GRN)*8)  // 38592 shorts = 77184 B

typedef short bfrag __attribute__((ext_vector_type(8)));
typedef float f4v  __attribute__((ext_vector_type(4)));

union U8 { unsigned short u[8]; uint4 v; };

__device__ __forceinline__ float sigf(float x){ return 1.0f/(1.0f+__expf(-x)); }

// pack high halves of two fp32 (bf16-valued) into one u32: [lo16=bf(f0), hi16=bf(f1)]
__device__ __forceinline__ unsigned int pkhi(unsigned int u1, unsigned int u0){
  return __builtin_amdgcn_perm(u1, u0, 0x07060302u);
}

// async 16B/lane global->LDS copy (wave-level: LDS dest = base + lane*16)
__device__ __forceinline__ void gload_lds16(const void* g, void* l){
  __builtin_amdgcn_global_load_lds(
      (const __attribute__((address_space(1))) void*)g,
      (__attribute__((address_space(3))) void*)l, 16, 0, 0);
}

// ---------------- K1: s1 = sigmoid(x @ W1 + b1) ----------------
__global__ void k1_s1(const float* __restrict__ x, const float* __restrict__ W1,
                      const float* __restrict__ b1, float* __restrict__ s1o){
  __shared__ float xs[16];
  int b = blockIdx.x, t = threadIdx.x;
  if(t < 16) xs[t] = x[b*16 + t];
  __syncthreads();
  for(int h = t; h < H_; h += 256){
    float acc = b1[h];
    #pragma unroll
    for(int j=0;j<16;j++) acc = __fmaf_rn(xs[j], W1[j*H_ + h], acc);
    s1o[(size_t)b*H_ + h] = sigf(acc);
  }
}

// ---------------- K2: s2 = sigmoid(softplus @ W2 + b2), softplus = -log(1-s1) ----
__global__ __launch_bounds__(256,3) void k2_s2(const float* __restrict__ s1,
                      const float* __restrict__ W2, const float* __restrict__ b2,
                      float* __restrict__ s2o){
  __shared__ __align__(16) float As[32*LDP0];
  __shared__ __align__(16) float Bs[32*LDP0];
  int t = threadIdx.x, tx = t & 15, ty = t >> 4;
  int m0 = blockIdx.x * 128, n0 = blockIdx.y * 128;
  int jj = t & 31, rb4 = (t >> 5) * 4;
  float acc[8][8];
  #pragma unroll
  for(int i=0;i<8;i++){
    #pragma unroll
    for(int k=0;k<8;k++) acc[i][k]=0.f; }

  for(int jt=0; jt<32; jt++){
    int j0 = jt*32;
    __syncthreads();
    #pragma unroll
    for(int g=0; g<4; g++){
      #pragma unroll
      for(int i=0;i<4;i++){
        int r = rb4 + i + 32*g;
        As[jj*LDP0 + r] = -__logf(1.0f - s1[(size_t)(m0+r)*H_ + j0 + jj]);
      }
    }
    { int jB = t >> 3, kb = (t & 7) * 16;
      const float* src = &W2[(size_t)(j0 + jB)*H_ + n0 + kb];
      #pragma unroll
      for(int c=0;c<4;c++) *(float4*)&Bs[jB*LDP0 + kb + 4*c] = *(const float4*)(src + 4*c);
    }
    __syncthreads();
    #pragma unroll 8
    for(int j=0;j<32;j++){
      float4 a0 = *(const float4*)&As[j*LDP0 + 8*ty];
      float4 a1f= *(const float4*)&As[j*LDP0 + 8*ty+4];
      float4 b0 = *(const float4*)&Bs[j*LDP0 + 4*tx];
      float4 b1f= *(const float4*)&Bs[j*LDP0 + 64 + 4*tx];
      float aa[8] = {a0.x,a0.y,a0.z,a0.w,a1f.x,a1f.y,a1f.z,a1f.w};
      float bb[8] = {b0.x,b0.y,b0.z,b0.w,b1f.x,b1f.y,b1f.z,b1f.w};
      #pragma unroll
      for(int i=0;i<8;i++){
        #pragma unroll
        for(int k=0;k<8;k++) acc[i][k] = __fmaf_rn(aa[i], bb[k], acc[i][k]); }
    }
  }
  float4 bb0 = *(const float4*)&b2[n0 + 4*tx];
  float4 bb1 = *(const float4*)&b2[n0 + 64 + 4*tx];
  #pragma unroll
  for(int i=0;i<8;i++){
    size_t r = (size_t)(m0 + 8*ty + i)*H_;
    float4 o0 = make_float4(sigf(acc[i][0]+bb0.x), sigf(acc[i][1]+bb0.y),
                            sigf(acc[i][2]+bb0.z), sigf(acc[i][3]+bb0.w));
    float4 o1 = make_float4(sigf(acc[i][4]+bb1.x), sigf(acc[i][5]+bb1.y),
                            sigf(acc[i][6]+bb1.z), sigf(acc[i][7]+bb1.w));
    *(float4*)&s2o[r + n0 + 4*tx] = o0;
    *(float4*)&s2o[r + n0 + 64 + 4*tx] = o1;
  }
}

// ---------------- K3: u = (w3*s2) @ W2^T ----------------
__global__ __launch_bounds__(256,3) void k3_u(const float* __restrict__ s2,
                      const float* __restrict__ W2, const float* __restrict__ W3,
                      float* __restrict__ u){
  __shared__ __align__(16) float As[32*LDP0];
  __shared__ __align__(16) float Bs[32*LDP0];
  int t = threadIdx.x, tx = t & 15, ty = t >> 4;
  int m0 = blockIdx.x * 128, n0 = blockIdx.y * 128;
  int jj = t & 31, rb4 = (t >> 5) * 4;
  float acc[8][8];
  #pragma unroll
  for(int i=0;i<8;i++){
    #pragma unroll
    for(int k=0;k<8;k++) acc[i][k]=0.f; }

  for(int kt=0; kt<32; kt++){
    int k0 = kt*32;
    __syncthreads();
    float w3v = W3[k0 + jj];
    #pragma unroll
    for(int g=0; g<4; g++){
      #pragma unroll
      for(int i=0;i<4;i++){
        int r = rb4 + i + 32*g;
        As[jj*LDP0 + r] = w3v * s2[(size_t)(m0+r)*H_ + k0 + jj];
      }
    }
    { int jcol = t >> 1, kb = (t & 1) * 16;
      const float* src = &W2[(size_t)(n0 + jcol)*H_ + k0 + kb];
      #pragma unroll
      for(int c=0;c<16;c++) Bs[(kb+c)*LDP0 + jcol] = src[c];
    }
    __syncthreads();
    #pragma unroll 8
    for(int j=0;j<32;j++){
      float4 a0 = *(const float4*)&As[j*LDP0 + 8*ty];
      float4 a1f= *(const float4*)&As[j*LDP0 + 8*ty+4];
      float4 b0 = *(const float4*)&Bs[j*LDP0 + 4*tx];
      float4 b1f= *(const float4*)&Bs[j*LDP0 + 64 + 4*tx];
      float aa[8] = {a0.x,a0.y,a0.z,a0.w,a1f.x,a1f.y,a1f.z,a1f.w};
      float bb[8] = {b0.x,b0.y,b0.z,b0.w,b1f.x,b1f.y,b1f.z,b1f.w};
      #pragma unroll
      for(int i=0;i<8;i++){
        #pragma unroll
        for(int k=0;k<8;k++) acc[i][k] = __fmaf_rn(aa[i], bb[k], acc[i][k]); }
    }
  }
  #pragma unroll
  for(int i=0;i<8;i++){
    size_t r = (size_t)(m0 + 8*ty + i)*H_;
    *(float4*)&u[r + n0 + 4*tx]      = make_float4(acc[i][0],acc[i][1],acc[i][2],acc[i][3]);
    *(float4*)&u[r + n0 + 64 + 4*tx] = make_float4(acc[i][4],acc[i][5],acc[i][6],acc[i][7]);
  }
}

// ---------------- KF: F64[j][p] = W1[8+(p>>3)][j]*W1[8+(p&7)][j] ----------------
__global__ void kF(const float* __restrict__ W1, float* __restrict__ F64){
  int e = blockIdx.x*256 + threadIdx.x;
  int j = e >> 6, p = e & 63;
  F64[e] = W1[(8+(p>>3))*H_ + j] * W1[(8+(p&7))*H_ + j];
}

// ---------------- K5a: Hz1M = D1 @ F64 ----------------
__global__ __launch_bounds__(256) void k5a(const float* __restrict__ s1,
                      const float* __restrict__ u, const float* __restrict__ F64,
                      float* __restrict__ Hz1M){
  __shared__ __align__(16) float As[32*72];
  __shared__ __align__(16) float Bs[32*72];
  int t = threadIdx.x, tx = t & 15, ty = t >> 4;
  int m0 = blockIdx.x * 64;
  int jj = t & 31, rb8 = (t >> 5) * 8;
  float acc[4][4];
  #pragma unroll
  for(int i=0;i<4;i++){
    #pragma unroll
    for(int k=0;k<4;k++) acc[i][k]=0.f; }

  for(int jt=0; jt<32; jt++){
    int j0 = jt*32;
    __syncthreads();
    #pragma unroll
    for(int g=0; g<8; g++){
      int r = rb8 + g;
      float s = s1[(size_t)(m0+r)*H_ + j0 + jj];
      As[jj*72 + r] = s*(1.0f-s)*u[(size_t)(m0+r)*H_ + j0 + jj];
    }
    { int jB = t >> 3, cb = (t & 7) * 8;
      const float* src = &F64[(j0 + jB)*64 + cb];
      *(float4*)&Bs[jB*72 + cb]   = *(const float4*)(src);
      *(float4*)&Bs[jB*72 + cb+4] = *(const float4*)(src+4);
    }
    __syncthreads();
    #pragma unroll 8
    for(int j=0;j<32;j++){
      float4 a4 = *(const float4*)&As[j*72 + 4*ty];
      float4 b4 = *(const float4*)&Bs[j*72 + 4*tx];
      float aa[4] = {a4.x,a4.y,a4.z,a4.w};
      float bb[4] = {b4.x,b4.y,b4.z,b4.w};
      #pragma unroll
      for(int i=0;i<4;i++){
        #pragma unroll
        for(int k=0;k<4;k++) acc[i][k] = __fmaf_rn(aa[i], bb[k], acc[i][k]); }
    }
  }
  #pragma unroll
  for(int i=0;i<4;i++)
    *(float4*)&Hz1M[(size_t)(m0+4*ty+i)*64 + 4*tx] =
      make_float4(acc[i][0],acc[i][1],acc[i][2],acc[i][3]);
}

// ---------------- K5b: dq16[b][0:8]=dLdq, [8:16]=c1 ----------------
__global__ void k5b(const float* __restrict__ s1, const float* __restrict__ u,
                    const float* __restrict__ W1, const float* __restrict__ x,
                    float* __restrict__ dq16){
  int wid = threadIdx.x >> 6, lane = threadIdx.x & 63;
  int b = blockIdx.x*4 + wid;
  float qd[8];
  #pragma unroll
  for(int i=0;i<8;i++) qd[i] = x[b*16 + 8 + i];
  float accd[8] = {0,0,0,0,0,0,0,0};
  float accc[8] = {0,0,0,0,0,0,0,0};
  for(int jb=0;jb<16;jb++){
    int j = jb*64 + lane;
    float s1v = s1[(size_t)b*H_+j], uv = u[(size_t)b*H_+j];
    float g1 = s1v*uv;
    float d1 = (1.0f - s1v)*g1;
    float w1q = 0.f;
    #pragma unroll
    for(int i=0;i<8;i++){ float w = W1[i*H_+j];
      accd[i] = __fmaf_rn(g1, w, accd[i]);
      w1q = __fmaf_rn(qd[i], w, w1q); }
    float dw = d1*w1q;
    #pragma unroll
    for(int m=0;m<8;m++) accc[m] = __fmaf_rn(dw, W1[(8+m)*H_+j], accc[m]);
  }
  #pragma unroll
  for(int i=0;i<8;i++){
    #pragma unroll
    for(int off=1; off<64; off<<=1){
      accd[i] += __shfl_xor(accd[i], off, 64);
      accc[i] += __shfl_xor(accc[i], off, 64);
    }
  }
  if(lane==0){
    #pragma unroll
    for(int i=0;i<8;i++){ dq16[b*16+i] = accd[i]; dq16[b*16+8+i] = accc[i]; }
  }
}

// ---------------- KW2T: W2 -> 3 transposed bf16 EXACT-truncation planes [k][j] ----
__global__ void kW2T(const float* __restrict__ W2, unsigned short* __restrict__ Wh,
                     unsigned short* __restrict__ Wm, unsigned short* __restrict__ Wl){
  __shared__ float tile[32][132];
  int j0 = blockIdx.x * 32, k0 = blockIdx.y * 128;
  int t = threadIdx.x;
  int lr = t >> 3, lc0 = (t & 7) * 16;
  const float* src = &W2[(size_t)(j0+lr)*H_ + k0 + lc0];
  #pragma unroll
  for(int c=0;c<16;c+=4) *(float4*)&tile[lr][lc0+c] = *(const float4*)(src + c);
  __syncthreads();
  int k = t >> 1;
  #pragma unroll
  for(int o2=0;o2<2;o2++){
    int oc = (t&1)*2 + o2;
    U8 uh, um2, ul2;
    #pragma unroll
    for(int e=0;e<8;e++){
      float a = tile[oc*8+e][k];
      unsigned int ua = __float_as_uint(a);
      unsigned int h = ua & 0xFFFF0000u;
      float r1 = __fsub_rn(a, __uint_as_float(h));        // exact, contraction-proof
      unsigned int m = __float_as_uint(r1) & 0xFFFF0000u;
      float l = __fsub_rn(r1, __uint_as_float(m));        // exactly bf16-representable
      uh.u[e]  = (unsigned short)(h >> 16);
      um2.u[e] = (unsigned short)(m >> 16);
      ul2.u[e] = (unsigned short)(__float_as_uint(l) >> 16);
    }
    size_t o = (size_t)(k0+k)*H_ + j0 + oc*8;
    *(uint4*)&Wh[o] = uh.v; *(uint4*)&Wm[o] = um2.v; *(uint4*)&Wl[o] = ul2.v;
  }
}

// ---------------- K4: bf16x8 exact-split MFMA T-GEMM + d2 contraction ----------------
// Block: 16 samples x 256 k-cols. Grid 2048 = 512 sgp x 4 kb2.
// B staging uses async global_load_lds (12 wave-ops/wave/jt, 1KB each):
// LDS dest is linear (base + lane*16); the SOURCE row is pre-swizzled with the
// same involution perm(g)=g^((g&8)>>1) used by the layout, so the LDS bytes are
// bit-identical to manual stores (source-permute == dest-permute for an
// involution). Latency hides under the A-split stage; syncthreads drains vmcnt
// before the MFMA phase. 2-barrier/jt structure. Session-final design notes:
//  - compiler scheduling beats manual phase-interleave (round 9: -15%)
//  - B-in-registers spills at any occupancy setting (rounds 6/11: GB WRITE_SIZE)
//  - conflict counter tracks LDS op volume, not fixable aliasing (rounds 5-11)
__global__ __launch_bounds__(256,2) void k4_mfma(
    const float* __restrict__ s1, const float* __restrict__ s2,
    const float* __restrict__ x,  const float* __restrict__ W1,
    const unsigned short* __restrict__ W2Th, const unsigned short* __restrict__ W2Tm,
    const unsigned short* __restrict__ W2Tl,
    const float* __restrict__ W3, float* __restrict__ Mpart){
  __shared__ union {
    unsigned short AB[AB2_SH];
    float Td[64*LDT];
  } sm;
  __shared__ float qds[16][8];

  int t = threadIdx.x;
  int wv = t >> 6, lane = t & 63;
  int kb2 = blockIdx.x & 3, sgp = blockIdx.x >> 2;
  int b0 = sgp*16, k0 = kb2*256;

  if(t < 128){ int s = t>>3, i = t&7; qds[s][i] = x[(b0+s)*16 + 8+i]; }

  f4v acc[9][4];
  #pragma unroll
  for(int mt=0;mt<9;mt++){
    #pragma unroll
    for(int n2=0;n2<4;n2++){ acc[mt][n2][0]=0.f; acc[mt][n2][1]=0.f; acc[mt][n2][2]=0.f; acc[mt][n2][3]=0.f; }
  }

  int aoct = t & 3, arow = t >> 2;
  int fr_m = lane & 15, fr_q = lane >> 4;
  // swizzled fragment-read granule bases (jt-invariant)
  int pfm   = fr_m ^ ((fr_m & 8) >> 1);
  int aRd   = fr_q*A_SEC + pfm;                        // + p*4*A_SEC + mt*16
  int bRd   = A_GRN + fr_q*B2_SEC + wv*64 + pfm;       // + p*4*B2_SEC + n2*16

  for(int jt=0; jt<32; jt++){
    int j0 = jt*32;
    __syncthreads();
    // ---- B stage: 48 async 1KB global->LDS copies (12 per wave) ----
    {
      #pragma unroll
      for(int i=0;i<12;i++){
        int fid = wv*12 + i;                 // 0..47
        int p = fid >> 4, rem = fid & 15;
        int oc = rem >> 2, run = rem & 3;
        int g  = run*64 + lane;              // granule index within section
        int row = g ^ ((g & 8) >> 1);        // pre-swizzled source row (involution)
        const unsigned short* gp = (p==0) ? W2Th : ((p==1) ? W2Tm : W2Tl);
        const unsigned short* ga = &gp[(size_t)(k0+row)*H_ + j0 + oc*8];
        unsigned short* la = (unsigned short*)&sm.AB[(size_t)(A_GRN + (p*4+oc)*B2_SEC + run*64)*8];
        gload_lds16(ga, la);
      }
    }
    // ---- A stage: 144 rows x 32 j, exact 3-way truncation split ----
    #pragma unroll
    for(int pass=0; pass<3; pass++){
      int r = pass*64 + arow;
      if(r < 144){
        float4 w0, w1v, sa, sb;
        if(r < 128){
          int s = r>>3, m = r&7;
          const float* wp = &W1[(size_t)(8+m)*H_ + j0 + aoct*8];
          w0 = *(const float4*)wp; w1v = *(const float4*)(wp+4);
          const float* sp = &s1[(size_t)(b0+s)*H_ + j0 + aoct*8];
          sa = *(const float4*)sp; sb = *(const float4*)(sp+4);
        } else {
          int s = r - 128;
          float g0=0,g1=0,g2=0,g3=0,g4=0,g5=0,g6=0,g7=0;
          #pragma unroll
          for(int i=0;i<8;i++){
            float q = qds[s][i];
            const float* wp = &W1[(size_t)i*H_ + j0 + aoct*8];
            float4 a0 = *(const float4*)wp, a1 = *(const float4*)(wp+4);
            g0 = __fmaf_rn(q, a0.x, g0); g1 = __fmaf_rn(q, a0.y, g1);
            g2 = __fmaf_rn(q, a0.z, g2); g3 = __fmaf_rn(q, a0.w, g3);
            g4 = __fmaf_rn(q, a1.x, g4); g5 = __fmaf_rn(q, a1.y, g5);
            g6 = __fmaf_rn(q, a1.z, g6); g7 = __fmaf_rn(q, a1.w, g7);
          }
          w0 = make_float4(g0,g1,g2,g3); w1v = make_float4(g4,g5,g6,g7);
          const float* sp = &s1[(size_t)(b0+s)*H_ + j0 + aoct*8];
          sa = *(const float4*)sp; sb = *(const float4*)(sp+4);
        }
        float av[8];
        av[0]=__fmul_rn(w0.x,sa.x); av[1]=__fmul_rn(w0.y,sa.y);
        av[2]=__fmul_rn(w0.z,sa.z); av[3]=__fmul_rn(w0.w,sa.w);
        av[4]=__fmul_rn(w1v.x,sb.x); av[5]=__fmul_rn(w1v.y,sb.y);
        av[6]=__fmul_rn(w1v.z,sb.z); av[7]=__fmul_rn(w1v.w,sb.w);
        unsigned int uh[8], um[8], ul[8];
        #pragma unroll
        for(int e=0;e<8;e++){
          unsigned int ua = __float_as_uint(av[e]);
          unsigned int h = ua & 0xFFFF0000u;
          float r1 = __fsub_rn(av[e], __uint_as_float(h));   // exact
          unsigned int m = __float_as_uint(r1) & 0xFFFF0000u;
          float l = __fsub_rn(r1, __uint_as_float(m));       // exact
          uh[e]=h; um[e]=m; ul[e]=__float_as_uint(l);
        }
        int g0i = aoct*A_SEC + (r ^ ((r & 8) >> 1));   // plane 0 granule
        uint4 vh = make_uint4(pkhi(uh[1],uh[0]), pkhi(uh[3],uh[2]), pkhi(uh[5],uh[4]), pkhi(uh[7],uh[6]));
        uint4 vm = make_uint4(pkhi(um[1],um[0]), pkhi(um[3],um[2]), pkhi(um[5],um[4]), pkhi(um[7],um[6]));
        uint4 vl = make_uint4(pkhi(ul[1],ul[0]), pkhi(ul[3],ul[2]), pkhi(ul[5],ul[4]), pkhi(ul[7],ul[6]));
        *(uint4*)&sm.AB[(g0i            )*8] = vh;
        *(uint4*)&sm.AB[(g0i + 4*A_SEC  )*8] = vm;
        *(uint4*)&sm.AB[(g0i + 8*A_SEC  )*8] = vl;
      }
    }
    __syncthreads();   // drains vmcnt(0) -> all async B copies landed
    // ---- MFMA: one K=32 step, 8 split-terms, smallest-first ----
    bfrag bf[4][3];
    #pragma unroll
    for(int n2=0;n2<4;n2++){
      #pragma unroll
      for(int p=0;p<3;p++) bf[n2][p] = *(bfrag*)&sm.AB[(bRd + p*4*B2_SEC + n2*16)*8];
    }
    #pragma unroll
    for(int mt=0; mt<9; mt++){
      bfrag a0 = *(bfrag*)&sm.AB[(aRd             + mt*16)*8];
      bfrag a1v= *(bfrag*)&sm.AB[(aRd + 4*A_SEC   + mt*16)*8];
      bfrag a2v= *(bfrag*)&sm.AB[(aRd + 8*A_SEC   + mt*16)*8];
      #pragma unroll
      for(int n2=0;n2<4;n2++){
        f4v c = acc[mt][n2];
        c = __builtin_amdgcn_mfma_f32_16x16x32_bf16(a2v, bf[n2][1], c, 0,0,0); // 2^-24
        c = __builtin_amdgcn_mfma_f32_16x16x32_bf16(a1v, bf[n2][2], c, 0,0,0); // 2^-24
        c = __builtin_amdgcn_mfma_f32_16x16x32_bf16(a2v, bf[n2][0], c, 0,0,0); // 2^-16
        c = __builtin_amdgcn_mfma_f32_16x16x32_bf16(a0,  bf[n2][2], c, 0,0,0); // 2^-16
        c = __builtin_amdgcn_mfma_f32_16x16x32_bf16(a1v, bf[n2][1], c, 0,0,0); // 2^-16
        c = __builtin_amdgcn_mfma_f32_16x16x32_bf16(a1v, bf[n2][0], c, 0,0,0); // 2^-8
        c = __builtin_amdgcn_mfma_f32_16x16x32_bf16(a0,  bf[n2][1], c, 0,0,0); // 2^-8
        c = __builtin_amdgcn_mfma_f32_16x16x32_bf16(a0,  bf[n2][0], c, 0,0,0); // 1
        acc[mt][n2] = c;
      }
    }
  }

  // ---- epilogue: 4 phases of (dump one wave's 64 cols) + d2 contraction ----
  // Phases 0,1 -> kb = 2*kb2; phases 2,3 -> kb = 2*kb2+1 (each 128-col group
  // accumulated in the same order as the 128-col kernel -> bit-identical).
  float Mp[44];
  #pragma unroll
  for(int i=0;i<44;i++) Mp[i]=0.f;
  int es = t>>4, ec = t&15;
  const float* s2p = &s2[(size_t)(b0+es)*H_ + k0];

  #pragma unroll
  for(int ph=0; ph<4; ph++){
    __syncthreads();
    if(wv == ph){
      #pragma unroll
      for(int mt=0; mt<9; mt++){
        #pragma unroll
        for(int n2=0;n2<4;n2++){
          int col = n2*16 + fr_m;
          int rowb = mt*16 + fr_q*4;
          #pragma unroll
          for(int rg=0;rg<4;rg++)
            sm.Td[col*LDT + rowb + rg] = acc[mt][n2][rg];
        }
      }
    }
    __syncthreads();
    float4 s2v = *(const float4*)&s2p[ph*64 + ec*4];
    float4 w3v = *(const float4*)&W3[k0 + ph*64 + ec*4];
    float dv[4] = { w3v.x*s2v.x*(1.f-s2v.x), w3v.y*s2v.y*(1.f-s2v.y),
                    w3v.z*s2v.z*(1.f-s2v.z), w3v.w*s2v.w*(1.f-s2v.w) };
    #pragma unroll
    for(int e=0;e<4;e++){
      int col = ec*4+e;
      const float* tp = &sm.Td[col*LDT + es*8];
      float4 t0 = *(const float4*)tp, t1 = *(const float4*)(tp+4);
      float T8[8] = {t0.x,t0.y,t0.z,t0.w,t1.x,t1.y,t1.z,t1.w};
      float vv = sm.Td[col*LDT + 128 + es];
      float d = dv[e];
      int ix=0;
      #pragma unroll
      for(int m=0;m<8;m++){
        float w = __fmul_rn(T8[m], d);
        Mp[36+m] = __fmaf_rn(w, vv, Mp[36+m]);
        #pragma unroll
        for(int n=m;n<8;n++){ Mp[ix] = __fmaf_rn(w, T8[n], Mp[ix]); ix++; }
      }
    }
    if(ph & 1){
      // reduce over the 16 column-group lanes and write this kb group
      #pragma unroll
      for(int i=0;i<44;i++){
        #pragma unroll
        for(int off=1; off<16; off<<=1) Mp[i] += __shfl_xor(Mp[i], off, 64);
      }
      if(ec==0){
        int kb = kb2*2 + (ph>>1);
        float* o = &Mpart[((size_t)(b0+es)*8 + kb)*44];
        #pragma unroll
        for(int i=0;i<44;i++) o[i] = Mp[i];
      }
      #pragma unroll
      for(int i=0;i<44;i++) Mp[i]=0.f;
    }
  }
}

// ---------------- K6: assemble + f64 solve ----------------
__global__ __launch_bounds__(64) void k6(const float* __restrict__ x,
                    const float* __restrict__ Hz1M, const float* __restrict__ Mpart,
                    const float* __restrict__ dq16, float* __restrict__ out){
  __shared__ double A[64][73];
  int t = threadIdx.x;
  int b = blockIdx.x*64 + t;
  double* Ar = A[t];
  float qd[8];
  #pragma unroll
  for(int j=0;j<8;j++) qd[j] = x[b*16 + 8 + j];
  double Ms[44];
  #pragma unroll
  for(int i=0;i<44;i++) Ms[i]=0.0;
  for(int kb=0;kb<8;kb++){
    const float* mp = &Mpart[((size_t)b*8+kb)*44];
    #pragma unroll
    for(int i=0;i<44;i++) Ms[i] += (double)mp[i];
  }
  #pragma unroll
  for(int i=0;i<8;i++){
    #pragma unroll
    for(int j=0;j<8;j++) Ar[i*9+j] = (double)Hz1M[(size_t)b*64 + i*8 + j];
    Ar[i*9+8] = (double)dq16[b*16+i] - (double)dq16[b*16+8+i] - Ms[36+i];
  }
  { int ix=0;
    for(int m=0;m<8;m++)
      for(int n=m;n<8;n++){
        Ar[m*9+n] += Ms[ix];
        if(n>m) Ar[n*9+m] += Ms[ix];
        ix++;
      }
  }
  for(int c=0;c<8;c++){
    int piv = c; double best = fabs(Ar[c*9+c]);
    for(int rr=c+1; rr<8; rr++){ double v = fabs(Ar[rr*9+c]); if(v>best){best=v;piv=rr;} }
    if(piv!=c){
      for(int cc=c; cc<9; cc++){ double tmp=Ar[c*9+cc]; Ar[c*9+cc]=Ar[piv*9+cc]; Ar[piv*9+cc]=tmp; }
    }
    double inv = 1.0/Ar[c*9+c];
    for(int rr=c+1; rr<8; rr++){
      double f = Ar[rr*9+c]*inv;
      for(int cc=c+1; cc<9; cc++) Ar[rr*9+cc] -= f*Ar[c*9+cc];
    }
  }
  double sol[8];
  #pragma unroll
  for(int i=7;i>=0;i--){
    double s = Ar[i*9+8];
    #pragma unroll
    for(int j=i+1;j<8;j++) s -= Ar[i*9+j]*sol[j];
    sol[i] = s/Ar[i*9+i];
  }
  #pragma unroll
  for(int j=0;j<8;j++) out[b*16+j] = qd[j];
  #pragma unroll
  for(int i=0;i<8;i++) out[b*16+8+i] = (float)sol[i];
}

extern "C" void kernel_launch(void* const* d_in, const int* in_sizes, int n_in,
                              void* d_out, int out_size, void* d_ws, size_t ws_size,
                              hipStream_t stream){
  const float* x  = (const float*)d_in[0];
  const float* W1 = (const float*)d_in[1];
  const float* b1 = (const float*)d_in[2];
  const float* W2 = (const float*)d_in[3];
  const float* b2 = (const float*)d_in[4];
  const float* W3 = (const float*)d_in[5];
  float* out = (float*)d_out;

  float* ws   = (float*)d_ws;
  size_t BH   = (size_t)B_*H_;
  float* s1   = ws;                           // B*H
  float* s2   = s1  + BH;                     // B*H
  float* u    = s2  + BH;                     // B*H  (later: Mpart + W2T planes)
  float* F64  = u   + BH;                     // H*64
  float* Hz1M = F64 + (size_t)H_*64;          // B*64
  float* dq16 = Hz1M+ (size_t)B_*64;          // B*16

  // aliases inside u's 32 MB (u is dead after k5a/k5b):
  float* Mpart = u;                                        // B*8*44 fp32 = 11.5 MB
  unsigned short* W2Th = (unsigned short*)(u + 3145728);   // 12 MB offset, 2 MB
  unsigned short* W2Tm = W2Th + (size_t)H_*H_;             // 2 MB
  unsigned short* W2Tl = W2Tm + (size_t)H_*H_;             // 2 MB

  k1_s1 <<<dim3(B_),      dim3(256), 0, stream>>>(x, W1, b1, s1);
  k2_s2 <<<dim3(64,8),    dim3(256), 0, stream>>>(s1, W2, b2, s2);
  k3_u  <<<dim3(64,8),    dim3(256), 0, stream>>>(s2, W2, W3, u);
  kF    <<<dim3(256),     dim3(256), 0, stream>>>(W1, F64);
  k5a   <<<dim3(128),     dim3(256), 0, stream>>>(s1, u, F64, Hz1M);
  k5b   <<<dim3(2048),    dim3(256), 0, stream>>>(s1, u, W1, x, dq16);
  kW2T  <<<dim3(32,8),    dim3(256), 0, stream>>>(W2, W2Th, W2Tm, W2Tl);
  k4_mfma<<<dim3(2048),   dim3(256), 0, stream>>>(s1, s2, x, W1, W2Th, W2Tm, W2Tl, W3, Mpart);
  k6    <<<dim3(128),     dim3(64),  0, stream>>>(x, Hz1M, Mpart, dq16, out);
}